// Round 1
// baseline (133243.591 us; speedup 1.0000x reference)
//
#include <hip/hip_runtime.h>

#define T_LEN 262144
#define XBLK  64
#define NBLK  (T_LEN / XBLK)

// ---- DPP row-rotate helpers (self-calibrated usage; direction probed at runtime) ----
template<int N>
__device__ __forceinline__ int dppi(int v) {
    if constexpr (N == 0) return v;
    else return __builtin_amdgcn_update_dpp(v, v, 0x120 | N, 0xF, 0xF, false);
}
template<int N>
__device__ __forceinline__ float dppf(float v) {
    if constexpr (N == 0) return v;
    else return __int_as_float(
        __builtin_amdgcn_update_dpp(__float_as_int(v), __float_as_int(v), 0x120 | N, 0xF, 0xF, false));
}

__device__ __forceinline__ float sigm(float v) {
    return __builtin_amdgcn_rcpf(1.0f + __expf(-v));
}
__device__ __forceinline__ float tanh_(float v) {
    // tanh(x) = 1 - 2/(e^{2x}+1); exact at +-inf saturation, ~1e-6 rel error
    return 1.0f - 2.0f * __builtin_amdgcn_rcpf(__expf(2.0f * v) + 1.0f);
}

#define FOR16(M) M(0) M(1) M(2) M(3) M(4) M(5) M(6) M(7) M(8) M(9) M(10) M(11) M(12) M(13) M(14) M(15)

__global__ __launch_bounds__(64, 1) void lstm_seq(
    const float* __restrict__ x,
    const float* __restrict__ Wih0, const float* __restrict__ Whh0,
    const float* __restrict__ bih0, const float* __restrict__ bhh0,
    const float* __restrict__ Wih1, const float* __restrict__ Whh1,
    const float* __restrict__ bih1, const float* __restrict__ bhh1,
    const float* __restrict__ Wreg, const float* __restrict__ breg,
    float* __restrict__ out)
{
    const int L = threadIdx.x;   // 0..63 : gate row
    const int k = L & 15;        // hidden unit owned by this lane
    const int r = L >> 4;        // gate type row: 0=i 1=f 2=g 3=o

    // ---- probe actual DPP row_ror lane mapping (direction-proof) ----
    int smap[16];
#define PROBE(n) smap[n] = dppi<n>(k);
    FOR16(PROBE)

    // ---- gather weight rows pre-permuted to match the DPP rotation ----
    float w0p[16], wi1p[16], wh1p[16];
#pragma unroll
    for (int n = 0; n < 16; ++n) {
        int c = smap[n];
        w0p[n]  = Whh0[L * 16 + c];
        wi1p[n] = Wih1[L * 16 + c];
        wh1p[n] = Whh1[L * 16 + c];
    }
    float wx0[15];
#pragma unroll
    for (int j = 0; j < 15; ++j) wx0[j] = Wih0[L * 15 + j];

    const float gb0 = bih0[L] + bhh0[L];
    const float gb1 = bih1[L] + bhh1[L];

    const bool r0 = (r == 0), r1 = (r == 1), r2 = (r == 2), r3 = (r == 3);

    float h0m = 0.f, c0m = 0.f, h1m = 0.f, c1m = 0.f;

    __shared__ float xls[XBLK * 16];   // 64 steps x 16 floats (15 used, 1 pad) = 4 KiB

    // prologue: global-load block 0's x into regs
    float pref[15];
#pragma unroll
    for (int i = 0; i < 15; ++i) pref[i] = x[i * 64 + L];

    float xva[16], xvb[16];

    for (int blk = 0; blk < NBLK; ++blk) {
        // stage current block (held in regs) into LDS, padded to stride 16
#pragma unroll
        for (int i = 0; i < 15; ++i) {
            unsigned g = (unsigned)(i * 64 + L);
            unsigned t = g / 15u;
            unsigned j = g - t * 15u;
            xls[t * 16 + j] = pref[i];
        }
        // issue next block's global loads now (a full block of latency hiding)
        int nbase = (blk + 1 < NBLK ? blk + 1 : blk) * (XBLK * 15);
#pragma unroll
        for (int i = 0; i < 15; ++i) pref[i] = x[nbase + i * 64 + L];

        auto loadx = [&](float* xv, int s) {
            const float4* p = reinterpret_cast<const float4*>(&xls[s * 16]);
            *reinterpret_cast<float4*>(&xv[0])  = p[0];
            *reinterpret_cast<float4*>(&xv[4])  = p[1];
            *reinterpret_cast<float4*>(&xv[8])  = p[2];
            *reinterpret_cast<float4*>(&xv[12]) = p[3];
        };

        auto step = [&](const float* xv) {
            // ---------------- layer 0 ----------------
            float acc[4] = { gb0, 0.f, 0.f, 0.f };
#pragma unroll
            for (int j = 0; j < 15; ++j) acc[j & 3] = fmaf(wx0[j], xv[j], acc[j & 3]);
#define L0TERM(n) acc[(n) & 3] = fmaf(w0p[(n)], dppf<(n)>(h0m), acc[(n) & 3]);
            FOR16(L0TERM)
            float g0 = (acc[0] + acc[1]) + (acc[2] + acc[3]);
            // distribute the 4 gate types of unit k to every lane
            float e1 = __shfl_xor(g0, 16);
            float e2 = __shfl_xor(g0, 32);
            float e3 = __shfl_xor(e1, 32);
            float gi = r0 ? g0 : r1 ? e1 : r2 ? e2 : e3;
            float gf = r1 ? g0 : r0 ? e1 : r3 ? e2 : e3;
            float gg = r2 ? g0 : r3 ? e1 : r0 ? e2 : e3;
            float go = r3 ? g0 : r2 ? e1 : r1 ? e2 : e3;
            c0m = fmaf(sigm(gf), c0m, sigm(gi) * tanh_(gg));
            h0m = sigm(go) * tanh_(c0m);

            // ---------------- layer 1 ----------------
            float bcc[4] = { gb1, 0.f, 0.f, 0.f };
#define L1TERM(n) bcc[(n) & 3] = fmaf(wi1p[(n)], dppf<(n)>(h0m), bcc[(n) & 3]); \
                  bcc[(n) & 3] = fmaf(wh1p[(n)], dppf<(n)>(h1m), bcc[(n) & 3]);
            FOR16(L1TERM)
            float g1 = (bcc[0] + bcc[1]) + (bcc[2] + bcc[3]);
            float f1 = __shfl_xor(g1, 16);
            float f2 = __shfl_xor(g1, 32);
            float f3 = __shfl_xor(f1, 32);
            float hi = r0 ? g1 : r1 ? f1 : r2 ? f2 : f3;
            float hf = r1 ? g1 : r0 ? f1 : r3 ? f2 : f3;
            float hg = r2 ? g1 : r3 ? f1 : r0 ? f2 : f3;
            float ho = r3 ? g1 : r2 ? f1 : r1 ? f2 : f3;
            c1m = fmaf(sigm(hf), c1m, sigm(hi) * tanh_(hg));
            h1m = sigm(ho) * tanh_(c1m);
        };

        loadx(xva, 0);
        for (int s = 0; s < XBLK; s += 2) {
            loadx(xvb, s + 1);             // prefetch odd step
            step(xva);
            loadx(xva, (s + 2) & (XBLK - 1)); // prefetch next even (stale wrap at 62 is overwritten)
            step(xvb);
        }
    }

    // ---- regression head: out[p] = b_reg[p] + sum_k W_reg[p][k] * h1[k] ----
    float h1f[16];
#pragma unroll
    for (int m = 0; m < 16; ++m) h1f[m] = __shfl(h1m, m, 16);
    if (L < 10) {
        float o = breg[L];
#pragma unroll
        for (int m = 0; m < 16; ++m) o = fmaf(Wreg[L * 16 + m], h1f[m], o);
        out[L] = o;
    }
}

extern "C" void kernel_launch(void* const* d_in, const int* in_sizes, int n_in,
                              void* d_out, int out_size, void* d_ws, size_t ws_size,
                              hipStream_t stream) {
    const float* x    = (const float*)d_in[0];
    const float* Wih0 = (const float*)d_in[1];
    const float* Whh0 = (const float*)d_in[2];
    const float* bih0 = (const float*)d_in[3];
    const float* bhh0 = (const float*)d_in[4];
    const float* Wih1 = (const float*)d_in[5];
    const float* Whh1 = (const float*)d_in[6];
    const float* bih1 = (const float*)d_in[7];
    const float* bhh1 = (const float*)d_in[8];
    const float* Wreg = (const float*)d_in[9];
    const float* breg = (const float*)d_in[10];

    lstm_seq<<<1, 64, 0, stream>>>(x, Wih0, Whh0, bih0, bhh0,
                                   Wih1, Whh1, bih1, bhh1, Wreg, breg,
                                   (float*)d_out);
}

// Round 3
// 71967.120 us; speedup vs baseline: 1.8515x; 1.8515x over previous
//
#include <hip/hip_runtime.h>

#define T_LEN 262144
#define CHK   32
#define NCH   (T_LEN / CHK)

// ---- DPP row-rotate (self-calibrated via probe, validated in round 1) ----
template<int N>
__device__ __forceinline__ int dppi(int v) {
    if constexpr (N == 0) return v;
    else return __builtin_amdgcn_update_dpp(v, v, 0x120 | N, 0xF, 0xF, false);
}
template<int N>
__device__ __forceinline__ float dppf(float v) {
    if constexpr (N == 0) return v;
    else return __int_as_float(
        __builtin_amdgcn_update_dpp(__float_as_int(v), __float_as_int(v), 0x120 | N, 0xF, 0xF, false));
}

__device__ __forceinline__ float swz16f(float v) {   // lane ^= 16 (within 32-lane halves)
    return __int_as_float(__builtin_amdgcn_ds_swizzle(__float_as_int(v), 0x401F));
}

__device__ __forceinline__ void waitge(int* f, int v) {
    while (__hip_atomic_load(f, __ATOMIC_ACQUIRE, __HIP_MEMORY_SCOPE_WORKGROUP) < v)
        __builtin_amdgcn_s_sleep(2);
}
__device__ __forceinline__ void setcnt(int* f, int v, int lane) {
    if (lane == 0)
        __hip_atomic_store(f, v, __ATOMIC_RELEASE, __HIP_MEMORY_SCOPE_WORKGROUP);
}

// Fused LSTM cell, lane = (row r, unit k), gate preact g in-lane.
// rows: 0=i 1=f 2=g 3=o. One exp for the gate activation, one for tanh(c).
__device__ __forceinline__ void cell(float g, bool r1f, bool r2f, bool oddf,
                                     float& c, float& h) {
    float arg = g * (r2f ? -2.0f : -1.0f);
    float e   = __expf(arg);
    float t   = __builtin_amdgcn_rcpf(1.0f + e);
    float a   = r2f ? fmaf(2.0f, t, -1.0f) : t;        // row2: tanh(g), else sigmoid(g)
    float m   = __shfl_xor(a, 32);                     // row0<->row2, row1<->row3
    float po  = r1f ? m : a;                           // sigma_o on odd rows
    float po2 = swz16f(po);                            // ship sigma_o to even rows
    float fs  = r1f ? a : m;                           // sigma_f on odd rows
    float u   = (oddf ? fs : a) * (oddf ? c : m);      // even: si*tg ; odd: sf*c
    float cn  = u + swz16f(u);                         // c_new, replicated in all lanes
    float e2  = __expf(-2.0f * cn);
    // tanh(cn) = 2*sigmoid(2*cn) - 1  (round-2 bug was the sign of this fma)
    float tc  = fmaf(2.0f, __builtin_amdgcn_rcpf(1.0f + e2), -1.0f);
    c = cn;
    h = (oddf ? po : po2) * tc;
}

#define FOR16(M) M(0) M(1) M(2) M(3) M(4) M(5) M(6) M(7) M(8) M(9) M(10) M(11) M(12) M(13) M(14) M(15)
#define FOR12(M) M(4) M(5) M(6) M(7) M(8) M(9) M(10) M(11) M(12) M(13) M(14) M(15)

// Pre-GEMM: gx[t][L] = Wih0[L,:] . x[t,:] + (bih0+bhh0)[L]   (trivially parallel)
__global__ __launch_bounds__(256) void xprep(
    const float* __restrict__ x, const float* __restrict__ Wih0,
    const float* __restrict__ bih0, const float* __restrict__ bhh0,
    float* __restrict__ gx)
{
    int t = blockIdx.x * 4 + (threadIdx.x >> 6);
    int L = threadIdx.x & 63;
    float acc = bih0[L] + bhh0[L];
    const float* xr = x + (size_t)t * 15;
#pragma unroll
    for (int j = 0; j < 15; ++j) acc = fmaf(Wih0[L * 15 + j], xr[j], acc);
    gx[(size_t)t * 64 + L] = acc;
}

__global__ __launch_bounds__(192, 1) void lstm_pipe(
    const float* __restrict__ x, const float* __restrict__ gx, int useGx,
    const float* __restrict__ Wih0, const float* __restrict__ Whh0,
    const float* __restrict__ bih0, const float* __restrict__ bhh0,
    const float* __restrict__ Wih1, const float* __restrict__ Whh1,
    const float* __restrict__ bih1, const float* __restrict__ bhh1,
    const float* __restrict__ Wreg, const float* __restrict__ breg,
    float* __restrict__ out)
{
    __shared__ float gxring[2][CHK][64];   // 16 KB; aliased as [2][CHK][16] x-ring in fallback
    __shared__ float hv[2][CHK][128];      // 32 KB; [0..63]=h0 replicated, [64..127]=v1 partial
    __shared__ int flags[3];               // 0: chunks staged  1: layer0 done  2: layer1 done

    const int tid = threadIdx.x;
    const int wid = tid >> 6;
    const int L = tid & 63;
    const int k = L & 15;
    const int r = L >> 4;
    const bool r1f = (r == 1), r2f = (r == 2), oddf = (r & 1);

    if (tid == 0) { flags[0] = 0; flags[1] = 0; flags[2] = 0; }
    __syncthreads();

    // probe actual DPP rotation map (direction-proof, validated round 1)
    int smap[16];
#define PROBE(n) smap[n] = dppi<n>(k);
    FOR16(PROBE)
#undef PROBE

    if (wid == 2) {
        // ---------------- wave 2: stager ----------------
        if (useGx) {
            const float4* src = reinterpret_cast<const float4*>(gx);
            for (int n = 0; n < NCH; ++n) {
                if (n >= 2) waitge(&flags[1], n - 1);
                float4* dst = reinterpret_cast<float4*>(&gxring[n & 1][0][0]);
                const float4* s = src + (size_t)n * (CHK * 16);
#pragma unroll
                for (int ii = 0; ii < 8; ++ii)
                    dst[ii * 64 + L] = s[ii * 64 + L];
                setcnt(&flags[0], n + 1, L);
            }
        } else {
            float (*xr)[CHK][16] = reinterpret_cast<float (*)[CHK][16]>(&gxring[0][0][0]);
            for (int n = 0; n < NCH; ++n) {
                if (n >= 2) waitge(&flags[1], n - 1);
                const float* s = x + (size_t)n * (CHK * 15);
#pragma unroll
                for (int ii = 0; ii < 8; ++ii) {
                    int idx = ii * 64 + L;
                    if (idx < CHK * 15) {
                        int tt = idx / 15, j = idx - tt * 15;
                        xr[n & 1][tt][j] = s[idx];
                    }
                }
                setcnt(&flags[0], n + 1, L);
            }
        }
    } else if (wid == 0) {
        // ---------------- wave 0: layer 0 (+ 4/16 of Wih1.h0) ----------------
        float w0p[16], wi1p4[4];
#pragma unroll
        for (int n = 0; n < 16; ++n) w0p[n] = Whh0[L * 16 + smap[n]];
#pragma unroll
        for (int n = 0; n < 4; ++n) wi1p4[n] = Wih1[L * 16 + smap[n]];
        float wx0[15];
        float gb0 = bih0[L] + bhh0[L];
        if (!useGx) {
#pragma unroll
            for (int j = 0; j < 15; ++j) wx0[j] = Wih0[L * 15 + j];
        }
        float h0 = 0.f, c0 = 0.f;
        float (*xr)[CHK][16] = reinterpret_cast<float (*)[CHK][16]>(&gxring[0][0][0]);

        for (int n = 0; n < NCH; ++n) {
            waitge(&flags[0], n + 1);
            if (n >= 2) waitge(&flags[2], n - 1);
            const int sl = n & 1;

            auto hhpart = [&](float a0, int i) {
                float ac[4] = { a0, 0.f, 0.f, 0.f };
#define T0(n) ac[(n) & 3] = fmaf(dppf<n>(h0), w0p[n], ac[(n) & 3]);
                FOR16(T0)
#undef T0
                float g = (ac[0] + ac[1]) + (ac[2] + ac[3]);
                cell(g, r1f, r2f, oddf, c0, h0);
                float v1 = dppf<0>(h0) * wi1p4[0];
                v1 = fmaf(dppf<1>(h0), wi1p4[1], v1);
                v1 = fmaf(dppf<2>(h0), wi1p4[2], v1);
                v1 = fmaf(dppf<3>(h0), wi1p4[3], v1);
                hv[sl][i][L] = h0;
                hv[sl][i][64 + L] = v1;
            };

            if (useGx) {
                float gcur = gxring[sl][0][L];
                for (int i = 0; i < CHK; ++i) {
                    float gnext = (i + 1 < CHK) ? gxring[sl][i + 1][L] : 0.f;
                    hhpart(gcur, i);
                    gcur = gnext;
                }
            } else {
                float xva[16], xvb[16];
                auto loadx = [&](float* xv, int i) {
                    const float4* p = reinterpret_cast<const float4*>(&xr[sl][i][0]);
                    reinterpret_cast<float4*>(xv)[0] = p[0];
                    reinterpret_cast<float4*>(xv)[1] = p[1];
                    reinterpret_cast<float4*>(xv)[2] = p[2];
                    reinterpret_cast<float4*>(xv)[3] = p[3];
                };
                auto xdot = [&](const float* xv) {
                    float s0 = gb0, s1 = 0.f, s2 = 0.f, s3 = 0.f;
#pragma unroll
                    for (int j = 0; j < 15; ++j) {
                        float p = fmaf(wx0[j], xv[j], (j & 3) == 0 ? s0 : (j & 3) == 1 ? s1 : (j & 3) == 2 ? s2 : s3);
                        if ((j & 3) == 0) s0 = p; else if ((j & 3) == 1) s1 = p; else if ((j & 3) == 2) s2 = p; else s3 = p;
                    }
                    return (s0 + s1) + (s2 + s3);
                };
                loadx(xva, 0);
                for (int i = 0; i < CHK; i += 2) {
                    loadx(xvb, i + 1);
                    hhpart(xdot(xva), i);
                    loadx(xva, (i + 2 < CHK) ? i + 2 : i);
                    hhpart(xdot(xvb), i + 1);
                }
            }
            setcnt(&flags[1], n + 1, L);
        }
    } else {
        // ---------------- wave 1: layer 1 (12/16 of Wih1.h0 + Whh1.h1) ----------------
        float wi1p[16], wh1p[16];
#pragma unroll
        for (int n = 0; n < 16; ++n) {
            wi1p[n] = Wih1[L * 16 + smap[n]];
            wh1p[n] = Whh1[L * 16 + smap[n]];
        }
        const float gb1 = bih1[L] + bhh1[L];
        float h1 = 0.f, c1 = 0.f;
        float pa[4];

        for (int n = 0; n < NCH; ++n) {
            waitge(&flags[1], n + 1);
            const int sl = n & 1;
            float h0c = hv[sl][0][L];
            float v1c = hv[sl][0][64 + L];
            // wih-part for step 0 of this chunk
            pa[0] = gb1 + v1c; pa[1] = 0.f; pa[2] = 0.f; pa[3] = 0.f;
#define TW(n) pa[(n) & 3] = fmaf(dppf<n>(h0c), wi1p[n], pa[(n) & 3]);
            FOR12(TW)
#undef TW
            for (int i = 0; i < CHK; ++i) {
                float h0n = 0.f, v1n = 0.f;
                if (i + 1 < CHK) { h0n = hv[sl][i + 1][L]; v1n = hv[sl][i + 1][64 + L]; }
                float b[4] = { pa[0], pa[1], pa[2], pa[3] };
#define T1(n) b[(n) & 3] = fmaf(dppf<n>(h1), wh1p[n], b[(n) & 3]);
                FOR16(T1)
#undef T1
                float g1 = (b[0] + b[1]) + (b[2] + b[3]);
                cell(g1, r1f, r2f, oddf, c1, h1);
                // wih-part for step i+1 (independent of the cell above — overlaps exp latency)
                pa[0] = gb1 + v1n; pa[1] = 0.f; pa[2] = 0.f; pa[3] = 0.f;
#define TW(n) pa[(n) & 3] = fmaf(dppf<n>(h0n), wi1p[n], pa[(n) & 3]);
                FOR12(TW)
#undef TW
            }
            setcnt(&flags[2], n + 1, L);
        }

        // ---- regression head ----
        float h1f[16];
#pragma unroll
        for (int m = 0; m < 16; ++m) h1f[m] = __shfl(h1, m, 16);
        if (L < 10) {
            float o = breg[L];
#pragma unroll
            for (int m = 0; m < 16; ++m) o = fmaf(Wreg[L * 16 + m], h1f[m], o);
            out[L] = o;
        }
    }
}

extern "C" void kernel_launch(void* const* d_in, const int* in_sizes, int n_in,
                              void* d_out, int out_size, void* d_ws, size_t ws_size,
                              hipStream_t stream) {
    const float* x    = (const float*)d_in[0];
    const float* Wih0 = (const float*)d_in[1];
    const float* Whh0 = (const float*)d_in[2];
    const float* bih0 = (const float*)d_in[3];
    const float* bhh0 = (const float*)d_in[4];
    const float* Wih1 = (const float*)d_in[5];
    const float* Whh1 = (const float*)d_in[6];
    const float* bih1 = (const float*)d_in[7];
    const float* bhh1 = (const float*)d_in[8];
    const float* Wreg = (const float*)d_in[9];
    const float* breg = (const float*)d_in[10];

    const size_t need = (size_t)T_LEN * 64 * sizeof(float);
    int useGx = (d_ws != nullptr && ws_size >= need) ? 1 : 0;
    float* gx = (float*)d_ws;

    if (useGx)
        xprep<<<T_LEN / 4, 256, 0, stream>>>(x, Wih0, bih0, bhh0, gx);

    lstm_pipe<<<1, 192, 0, stream>>>(x, gx, useGx,
                                     Wih0, Whh0, bih0, bhh0,
                                     Wih1, Whh1, bih1, bhh1,
                                     Wreg, breg, (float*)d_out);
}

// Round 4
// 71499.042 us; speedup vs baseline: 1.8636x; 1.0065x over previous
//
#include <hip/hip_runtime.h>

#define T_LEN 262144
#define CHK   64
#define NCH   (T_LEN / CHK)
#define PFD   8
#define LOG2E 1.44269504088896340736f

typedef __attribute__((ext_vector_type(2))) unsigned int u32x2;

#if __has_builtin(__builtin_amdgcn_permlane32_swap) && __has_builtin(__builtin_amdgcn_permlane16_swap)
#define HAVE_PLSWAP 1
#else
#define HAVE_PLSWAP 0
#endif

#define FOR16(M) M(0) M(1) M(2) M(3) M(4) M(5) M(6) M(7) M(8) M(9) M(10) M(11) M(12) M(13) M(14) M(15)
#define FOR8HI(M) M(8) M(9) M(10) M(11) M(12) M(13) M(14) M(15)

// ---- DPP row-rotate (self-calibrated via probe, validated rounds 1/3) ----
template<int N>
__device__ __forceinline__ int dppi(int v) {
    if constexpr (N == 0) return v;
    else return __builtin_amdgcn_update_dpp(v, v, 0x120 | N, 0xF, 0xF, false);
}
template<int N>
__device__ __forceinline__ float dppf(float v) {
    if constexpr (N == 0) return v;
    else return __int_as_float(
        __builtin_amdgcn_update_dpp(__float_as_int(v), __float_as_int(v), 0x120 | N, 0xF, 0xF, false));
}

__device__ __forceinline__ float swz16f(float v) {   // lane ^= 16 (LDS pipe, fallback only)
    return __int_as_float(__builtin_amdgcn_ds_swizzle(__float_as_int(v), 0x401F));
}

// lo = low-half broadcast (v[L&31]); hi = high-half broadcast (v[32|(L&31)])
template<int MODE>
__device__ __forceinline__ void PL32(float a, float& lo, float& hi, int L) {
#if HAVE_PLSWAP
    if constexpr (MODE < 2) {
        u32x2 p = __builtin_amdgcn_permlane32_swap(__float_as_uint(a), __float_as_uint(a), false, false);
        float xx = __uint_as_float(p[0]), yy = __uint_as_float(p[1]);
        if constexpr (MODE == 0) { lo = xx; hi = yy; }
        else                     { lo = yy; hi = xx; }
        return;
    }
#endif
    float pr = __shfl_xor(a, 32);
    lo = (L & 32) ? pr : a;
    hi = (L & 32) ? a : pr;
}

// ev = even-16-row broadcast (v[L&~16]); od = odd-16-row broadcast (v[L|16])
template<int MODE>
__device__ __forceinline__ void PL16(float a, float& ev, float& od, int L) {
#if HAVE_PLSWAP
    if constexpr (MODE < 2) {
        u32x2 p = __builtin_amdgcn_permlane16_swap(__float_as_uint(a), __float_as_uint(a), false, false);
        float xx = __uint_as_float(p[0]), yy = __uint_as_float(p[1]);
        if constexpr (MODE == 0) { ev = xx; od = yy; }
        else                     { ev = yy; od = xx; }
        return;
    }
#endif
    float pr = swz16f(a);
    ev = (L & 16) ? pr : a;
    od = (L & 16) ? a : pr;
}

__device__ __forceinline__ void waitge(int* f, int v) {
    while (__hip_atomic_load(f, __ATOMIC_ACQUIRE, __HIP_MEMORY_SCOPE_WORKGROUP) < v)
        __builtin_amdgcn_s_sleep(1);
}
__device__ __forceinline__ void setcnt(int* f, int v, int lane) {
    if (lane == 0)
        __hip_atomic_store(f, v, __ATOMIC_RELEASE, __HIP_MEMORY_SCOPE_WORKGROUP);
}

// Fused LSTM cell. Row r = L>>4: 0=i 1=f 2=g 3=o. Gate preacts are in
// log2(e)-scaled domain (weights pre-multiplied); cn/h are natural.
template<int MODE>
__device__ __forceinline__ void cellT(float g, bool r2f, bool hi16, int L, float& c, float& h) {
    float arg = g * (r2f ? -2.0f : -1.0f);
    float t   = __builtin_amdgcn_rcpf(1.0f + exp2f(arg));
    float a   = r2f ? fmaf(2.0f, t, -1.0f) : t;      // sig(i), sig(f), tanh(g), sig(o)
    float lo, hi;
    PL32<MODE>(a, lo, hi, L);                        // lo = si/sf bcast ; hi = tg/so bcast
    float u = lo * (hi16 ? c : hi);                  // even16: si*tg ; odd16: sf*c
    float ev, od, s0e, s0o;
    PL16<MODE>(u, ev, od, L);
    PL16<MODE>(hi, s0e, s0o, L);                     // s0o = sig(o) everywhere (independent chain)
    float cn = ev + od;                              // order-independent sum
    float tc = fmaf(2.0f, __builtin_amdgcn_rcpf(1.0f + exp2f(-2.0f * LOG2E * cn)), -1.0f);
    c = cn;
    h = s0o * tc;
    (void)s0e;
}

// Pre-GEMM: gx[t][L] = log2e * (Wih0[L,:].x[t,:] + bih0[L]+bhh0[L])
__global__ __launch_bounds__(256) void xprep(
    const float* __restrict__ x, const float* __restrict__ Wih0,
    const float* __restrict__ bih0, const float* __restrict__ bhh0,
    float* __restrict__ gx)
{
    int t = blockIdx.x * 4 + (threadIdx.x >> 6);
    int L = threadIdx.x & 63;
    float acc = bih0[L] + bhh0[L];
    const float* xr = x + (size_t)t * 15;
#pragma unroll
    for (int j = 0; j < 15; ++j) acc = fmaf(Wih0[L * 15 + j], xr[j], acc);
    gx[(size_t)t * 64 + L] = acc * LOG2E;
}

template<int MODE, bool GX>
__device__ __forceinline__ void run_wave0(
    const float* __restrict__ gx, const float* __restrict__ x,
    const float* __restrict__ Whh0, const float* __restrict__ Wih1,
    const float* __restrict__ Wih0, const float* __restrict__ bih0,
    const float* __restrict__ bhh0,
    float (*hv)[CHK][128], int* flags, int L)
{
    const int k = L & 15;
    const bool r2f = ((L >> 4) == 2);
    const bool hi16 = (L & 16) != 0;
    int smap[16];
#define PR(n) smap[n] = dppi<n>(k);
    FOR16(PR)
#undef PR
    float w0p[16], wi1l[8];
#pragma unroll
    for (int n = 0; n < 16; ++n) w0p[n] = Whh0[L * 16 + smap[n]] * LOG2E;
#pragma unroll
    for (int n = 0; n < 8; ++n) wi1l[n] = Wih1[L * 16 + smap[n]] * LOG2E;
    float wx0[15];
    float gb0 = 0.f;
    if constexpr (!GX) {
        gb0 = (bih0[L] + bhh0[L]) * LOG2E;
#pragma unroll
        for (int j = 0; j < 15; ++j) wx0[j] = Wih0[L * 15 + j] * LOG2E;
    }

    float h0 = 0.f, c0 = 0.f;
    const float* gpL = gx + L;
    float pf[PFD];
    float xp[2][15];
    if constexpr (GX) {
#pragma unroll
        for (int j = 0; j < PFD; ++j) pf[j] = gpL[(size_t)j * 64];
    } else {
#pragma unroll
        for (int j = 0; j < 15; ++j) { xp[0][j] = x[j]; xp[1][j] = x[15 + j]; }
    }

    for (int n = 0; n < NCH; ++n) {
        if (n >= 2) waitge(&flags[2], n - 1);
        const int sl = n & 1;
        for (int ib = 0; ib < CHK; ib += PFD) {
#pragma unroll
            for (int j = 0; j < PFD; ++j) {
                const int i = ib + j;
                float a0;
                if constexpr (GX) {
                    a0 = pf[j];
                    int nidx = n * CHK + i + PFD;
                    if (nidx > T_LEN - 1) nidx = T_LEN - 1;
                    pf[j] = gpL[(size_t)nidx * 64];
                } else {
                    a0 = gb0;
#pragma unroll
                    for (int q = 0; q < 15; ++q) a0 = fmaf(wx0[q], xp[j & 1][q], a0);
                    int nidx = n * CHK + i + 2;
                    if (nidx > T_LEN - 1) nidx = T_LEN - 1;
                    const float* xr = x + (size_t)nidx * 15;
#pragma unroll
                    for (int q = 0; q < 15; ++q) xp[j & 1][q] = xr[q];
                }
                float ac[4] = { a0, 0.f, 0.f, 0.f };
#define T0(m) ac[(m) & 3] = fmaf(dppf<m>(h0), w0p[m], ac[(m) & 3]);
                FOR16(T0)
#undef T0
                float g = (ac[0] + ac[1]) + (ac[2] + ac[3]);
                cellT<MODE>(g, r2f, hi16, L, c0, h0);
                hv[sl][i][L] = h0;
                float vv = dppf<0>(h0) * wi1l[0];
#define TV(m) vv = fmaf(dppf<m>(h0), wi1l[m], vv);
                TV(1) TV(2) TV(3) TV(4) TV(5) TV(6) TV(7)
#undef TV
                hv[sl][i][64 + L] = vv;
            }
        }
        setcnt(&flags[1], n + 1, L);
    }
}

template<int MODE>
__device__ __forceinline__ void run_wave1(
    const float* __restrict__ Wih1, const float* __restrict__ Whh1,
    const float* __restrict__ bih1, const float* __restrict__ bhh1,
    const float* __restrict__ Wreg, const float* __restrict__ breg,
    float (*hv)[CHK][128], int* flags, int L, float* __restrict__ out)
{
    const int k = L & 15;
    const bool r2f = ((L >> 4) == 2);
    const bool hi16 = (L & 16) != 0;
    int smap[16];
#define PR(n) smap[n] = dppi<n>(k);
    FOR16(PR)
#undef PR
    float wi1h[8], wh1p[16];
#pragma unroll
    for (int n = 0; n < 8; ++n) wi1h[n] = Wih1[L * 16 + smap[n + 8]] * LOG2E;
#pragma unroll
    for (int n = 0; n < 16; ++n) wh1p[n] = Whh1[L * 16 + smap[n]] * LOG2E;
    const float gb1 = (bih1[L] + bhh1[L]) * LOG2E;

    float h1 = 0.f, c1 = 0.f;
    float pa[4];

    for (int n = 0; n < NCH; ++n) {
        waitge(&flags[1], n + 1);
        const int sl = n & 1;
        float h0c = hv[sl][0][L];
        float v1c = hv[sl][0][64 + L];
        pa[0] = gb1 + v1c; pa[1] = 0.f; pa[2] = 0.f; pa[3] = 0.f;
#define TW(m) pa[(m) & 3] = fmaf(dppf<m>(h0c), wi1h[(m) - 8], pa[(m) & 3]);
        FOR8HI(TW)
#undef TW
        for (int i = 0; i < CHK; ++i) {
            float h0n = 0.f, v1n = 0.f;
            if (i + 1 < CHK) { h0n = hv[sl][i + 1][L]; v1n = hv[sl][i + 1][64 + L]; }
            float b[4] = { pa[0], pa[1], pa[2], pa[3] };
#define T1(m) b[(m) & 3] = fmaf(dppf<m>(h1), wh1p[m], b[(m) & 3]);
            FOR16(T1)
#undef T1
            float g1 = (b[0] + b[1]) + (b[2] + b[3]);
            cellT<MODE>(g1, r2f, hi16, L, c1, h1);
            pa[0] = gb1 + v1n; pa[1] = 0.f; pa[2] = 0.f; pa[3] = 0.f;
#define TW(m) pa[(m) & 3] = fmaf(dppf<m>(h0n), wi1h[(m) - 8], pa[(m) & 3]);
            FOR8HI(TW)
#undef TW
        }
        setcnt(&flags[2], n + 1, L);
    }

    float h1f[16];
#pragma unroll
    for (int m = 0; m < 16; ++m) h1f[m] = __shfl(h1, m, 16);
    if (L < 10) {
        float o = breg[L];
#pragma unroll
        for (int m = 0; m < 16; ++m) o = fmaf(Wreg[L * 16 + m], h1f[m], o);
        out[L] = o;
    }
}

__global__ __launch_bounds__(128, 1) void lstm_pipe(
    const float* __restrict__ x, const float* __restrict__ gx, int useGx,
    const float* __restrict__ Wih0, const float* __restrict__ Whh0,
    const float* __restrict__ bih0, const float* __restrict__ bhh0,
    const float* __restrict__ Wih1, const float* __restrict__ Whh1,
    const float* __restrict__ bih1, const float* __restrict__ bhh1,
    const float* __restrict__ Wreg, const float* __restrict__ breg,
    float* __restrict__ out)
{
    __shared__ float hv[2][CHK][128];   // 64 KB ring: [0..63]=h0 replicated, [64..127]=v1 partial
    __shared__ int flags[4];            // 1: layer0 chunks done  2: layer1 chunks done

    const int tid = threadIdx.x;
    const int wid = tid >> 6;
    const int L = tid & 63;

    if (tid == 0) { flags[0] = 0; flags[1] = 0; flags[2] = 0; flags[3] = 0; }
    __syncthreads();

    // ---- runtime probe of permlane*_swap pair-return order (order-proof) ----
    int MODE = 2;
#if HAVE_PLSWAP
    {
        u32x2 p = __builtin_amdgcn_permlane32_swap((unsigned)L, (unsigned)L, false, false);
        u32x2 q = __builtin_amdgcn_permlane16_swap((unsigned)L, (unsigned)L, false, false);
        bool m0 = (p[0] == (unsigned)(L & 31)) && (q[0] == (unsigned)(L & ~16));
        bool m1 = (p[1] == (unsigned)(L & 31)) && (q[1] == (unsigned)(L & ~16));
        if (__all(m0)) MODE = 0;
        else if (__all(m1)) MODE = 1;
    }
#endif

    if (wid == 0) {
        if (useGx) {
            switch (MODE) {
            case 0:  run_wave0<0, true>(gx, x, Whh0, Wih1, Wih0, bih0, bhh0, hv, flags, L); break;
            case 1:  run_wave0<1, true>(gx, x, Whh0, Wih1, Wih0, bih0, bhh0, hv, flags, L); break;
            default: run_wave0<2, true>(gx, x, Whh0, Wih1, Wih0, bih0, bhh0, hv, flags, L); break;
            }
        } else {
            switch (MODE) {
            case 0:  run_wave0<0, false>(gx, x, Whh0, Wih1, Wih0, bih0, bhh0, hv, flags, L); break;
            case 1:  run_wave0<1, false>(gx, x, Whh0, Wih1, Wih0, bih0, bhh0, hv, flags, L); break;
            default: run_wave0<2, false>(gx, x, Whh0, Wih1, Wih0, bih0, bhh0, hv, flags, L); break;
            }
        }
    } else {
        switch (MODE) {
        case 0:  run_wave1<0>(Wih1, Whh1, bih1, bhh1, Wreg, breg, hv, flags, L, out); break;
        case 1:  run_wave1<1>(Wih1, Whh1, bih1, bhh1, Wreg, breg, hv, flags, L, out); break;
        default: run_wave1<2>(Wih1, Whh1, bih1, bhh1, Wreg, breg, hv, flags, L, out); break;
        }
    }
}

extern "C" void kernel_launch(void* const* d_in, const int* in_sizes, int n_in,
                              void* d_out, int out_size, void* d_ws, size_t ws_size,
                              hipStream_t stream) {
    const float* x    = (const float*)d_in[0];
    const float* Wih0 = (const float*)d_in[1];
    const float* Whh0 = (const float*)d_in[2];
    const float* bih0 = (const float*)d_in[3];
    const float* bhh0 = (const float*)d_in[4];
    const float* Wih1 = (const float*)d_in[5];
    const float* Whh1 = (const float*)d_in[6];
    const float* bih1 = (const float*)d_in[7];
    const float* bhh1 = (const float*)d_in[8];
    const float* Wreg = (const float*)d_in[9];
    const float* breg = (const float*)d_in[10];

    const size_t need = (size_t)T_LEN * 64 * sizeof(float);
    int useGx = (d_ws != nullptr && ws_size >= need) ? 1 : 0;
    float* gx = (float*)d_ws;

    if (useGx)
        xprep<<<T_LEN / 4, 256, 0, stream>>>(x, Wih0, bih0, bhh0, gx);

    lstm_pipe<<<1, 128, 0, stream>>>(x, gx, useGx,
                                     Wih0, Whh0, bih0, bhh0,
                                     Wih1, Whh1, bih1, bhh1,
                                     Wreg, breg, (float*)d_out);
}

// Round 7
// 65906.470 us; speedup vs baseline: 2.0217x; 1.0849x over previous
//
#include <hip/hip_runtime.h>

#define T_LEN 262144
#define CHK   64
#define NCH   (T_LEN / CHK)
#define PFD   8
#define LOG2E 1.44269504088896340736f
#define N2LOG2E (-2.88539008177792681472f)

#define FOR16(M) M(0) M(1) M(2) M(3) M(4) M(5) M(6) M(7) M(8) M(9) M(10) M(11) M(12) M(13) M(14) M(15)
#define FOR8HI(M) M(8) M(9) M(10) M(11) M(12) M(13) M(14) M(15)

// ---- DPP row-rotate (self-calibrated via probe, validated rounds 1/3/4) ----
template<int N>
__device__ __forceinline__ int dppi(int v) {
    if constexpr (N == 0) return v;
    else return __builtin_amdgcn_update_dpp(v, v, 0x120 | N, 0xF, 0xF, false);
}
template<int N>
__device__ __forceinline__ float dppf(float v) {
    if constexpr (N == 0) return v;
    else return __int_as_float(
        __builtin_amdgcn_update_dpp(__float_as_int(v), __float_as_int(v), 0x120 | N, 0xF, 0xF, false));
}

__device__ __forceinline__ void waitge(int* f, int v) {
    while (__hip_atomic_load(f, __ATOMIC_ACQUIRE, __HIP_MEMORY_SCOPE_WORKGROUP) < v)
        __builtin_amdgcn_s_sleep(1);
}
__device__ __forceinline__ void setcnt(int* f, int v, int lane) {
    if (lane == 0)
        __hip_atomic_store(f, v, __ATOMIC_RELEASE, __HIP_MEMORY_SCOPE_WORKGROUP);
}

// Fused LSTM cell, parallel-gather form. Rows r=L>>4: 0=i 1=f 2=g 3=o.
// Preacts g arrive log2(e)-scaled. Each lane computes its row's activation,
// gathers the other three via 3 INDEPENDENT shfl_xor (one pipelined LDS
// latency instead of 2-3 serial), then computes the whole cell in-lane.
__device__ __forceinline__ void cell(float g, bool r2f, bool b0, bool b1,
                                     float& c, float& h) {
    float arg = g * (r2f ? -2.0f : -1.0f);
    float t   = __builtin_amdgcn_rcpf(1.0f + exp2f(arg));
    float a   = r2f ? fmaf(2.0f, t, -1.0f) : t;   // act(r): si, sf, tanh(g), so
    float a1 = __shfl_xor(a, 16);                 // act(r^1)
    float a2 = __shfl_xor(a, 32);                 // act(r^2)
    float a3 = __shfl_xor(a, 48);                 // act(r^3)
    float si = b1 ? (b0 ? a3 : a2) : (b0 ? a1 : a );
    float sf = b1 ? (b0 ? a2 : a3) : (b0 ? a  : a1);
    float tg = b1 ? (b0 ? a1 : a ) : (b0 ? a3 : a2);
    float so = b1 ? (b0 ? a  : a1) : (b0 ? a2 : a3);
    float cn = fmaf(sf, c, si * tg);
    float tc = fmaf(2.0f, __builtin_amdgcn_rcpf(1.0f + exp2f(N2LOG2E * cn)), -1.0f);
    c = cn;
    h = so * tc;
}

// Pre-GEMM: gx[t][L] = log2e * (Wih0[L,:].x[t,:] + bih0[L]+bhh0[L])
__global__ __launch_bounds__(256) void xprep(
    const float* __restrict__ x, const float* __restrict__ Wih0,
    const float* __restrict__ bih0, const float* __restrict__ bhh0,
    float* __restrict__ gx)
{
    int t = blockIdx.x * 4 + (threadIdx.x >> 6);
    int L = threadIdx.x & 63;
    float acc = bih0[L] + bhh0[L];
    const float* xr = x + (size_t)t * 15;
#pragma unroll
    for (int j = 0; j < 15; ++j) acc = fmaf(Wih0[L * 15 + j], xr[j], acc);
    gx[(size_t)t * 64 + L] = acc * LOG2E;
}

template<bool GX>
__device__ __forceinline__ void run_wave0(
    const float* __restrict__ gx, const float* __restrict__ x,
    const float* __restrict__ Whh0, const float* __restrict__ Wih1,
    const float* __restrict__ Wih0, const float* __restrict__ bih0,
    const float* __restrict__ bhh0,
    float (*hv)[CHK][128], int* flags, int L)
{
    const int k = L & 15;
    const int r = L >> 4;
    const bool r2f = (r == 2);
    const bool b0 = (r & 1), b1 = (r & 2);
    int smap[16];
#define PR(n) smap[n] = dppi<n>(k);
    FOR16(PR)
#undef PR
    float w0p[16], wi1l[8];
#pragma unroll
    for (int n = 0; n < 16; ++n) w0p[n] = Whh0[L * 16 + smap[n]] * LOG2E;
#pragma unroll
    for (int n = 0; n < 8; ++n) wi1l[n] = Wih1[L * 16 + smap[n]] * LOG2E;
    float wx0[15];
    float gb0 = 0.f;
    if constexpr (!GX) {
        gb0 = (bih0[L] + bhh0[L]) * LOG2E;
#pragma unroll
        for (int j = 0; j < 15; ++j) wx0[j] = Wih0[L * 15 + j] * LOG2E;
    }

    float h0 = 0.f, c0 = 0.f;
    const float* gpL = gx + L;
    float pf[PFD];
    float xp[2][15];
    if constexpr (GX) {
#pragma unroll
        for (int j = 0; j < PFD; ++j) pf[j] = gpL[(size_t)j * 64];
    } else {
#pragma unroll
        for (int j = 0; j < 15; ++j) { xp[0][j] = x[j]; xp[1][j] = x[15 + j]; }
    }

    for (int n = 0; n < NCH; ++n) {
        if (n >= 2) waitge(&flags[2], n - 1);
        const int sl = n & 1;
        for (int ib = 0; ib < CHK; ib += PFD) {
#pragma unroll
            for (int j = 0; j < PFD; ++j) {
                const int i = ib + j;
                float a0;
                if constexpr (GX) {
                    a0 = pf[j];
                    int nidx = n * CHK + i + PFD;
                    if (nidx > T_LEN - 1) nidx = T_LEN - 1;
                    pf[j] = gpL[(size_t)nidx * 64];
                } else {
                    a0 = gb0;
#pragma unroll
                    for (int q = 0; q < 15; ++q) a0 = fmaf(wx0[q], xp[j & 1][q], a0);
                    int nidx = n * CHK + i + 2;
                    if (nidx > T_LEN - 1) nidx = T_LEN - 1;
                    const float* xr = x + (size_t)nidx * 15;
#pragma unroll
                    for (int q = 0; q < 15; ++q) xp[j & 1][q] = xr[q];
                }
                float ac[4] = { a0, 0.f, 0.f, 0.f };
#define T0(m) ac[(m) & 3] = fmaf(dppf<m>(h0), w0p[m], ac[(m) & 3]);
                FOR16(T0)
#undef T0
                float g = (ac[0] + ac[1]) + (ac[2] + ac[3]);
                cell(g, r2f, b0, b1, c0, h0);
                hv[sl][i][L] = h0;
                float vv = dppf<0>(h0) * wi1l[0];
#define TV(m) vv = fmaf(dppf<m>(h0), wi1l[m], vv);
                TV(1) TV(2) TV(3) TV(4) TV(5) TV(6) TV(7)
#undef TV
                hv[sl][i][64 + L] = vv;
            }
        }
        setcnt(&flags[1], n + 1, L);
    }
}

__device__ __forceinline__ void run_wave1(
    const float* __restrict__ Wih1, const float* __restrict__ Whh1,
    const float* __restrict__ bih1, const float* __restrict__ bhh1,
    const float* __restrict__ Wreg, const float* __restrict__ breg,
    float (*hv)[CHK][128], int* flags, int L, float* __restrict__ out)
{
    const int k = L & 15;
    const int r = L >> 4;
    const bool r2f = (r == 2);
    const bool b0 = (r & 1), b1 = (r & 2);
    int smap[16];
#define PR(n) smap[n] = dppi<n>(k);
    FOR16(PR)
#undef PR
    float wi1h[8], wh1p[16];
#pragma unroll
    for (int n = 0; n < 8; ++n) wi1h[n] = Wih1[L * 16 + smap[n + 8]] * LOG2E;
#pragma unroll
    for (int n = 0; n < 16; ++n) wh1p[n] = Whh1[L * 16 + smap[n]] * LOG2E;
    const float gb1 = (bih1[L] + bhh1[L]) * LOG2E;

    float h1 = 0.f, c1 = 0.f;
    float pa[4];

    for (int n = 0; n < NCH; ++n) {
        waitge(&flags[1], n + 1);
        const int sl = n & 1;
        float h0c = hv[sl][0][L];
        float v1c = hv[sl][0][64 + L];
        pa[0] = gb1 + v1c; pa[1] = 0.f; pa[2] = 0.f; pa[3] = 0.f;
#define TW(m) pa[(m) & 3] = fmaf(dppf<m>(h0c), wi1h[(m) - 8], pa[(m) & 3]);
        FOR8HI(TW)
#undef TW
        for (int i = 0; i < CHK; ++i) {
            float h0n = 0.f, v1n = 0.f;
            if (i + 1 < CHK) { h0n = hv[sl][i + 1][L]; v1n = hv[sl][i + 1][64 + L]; }
            float b[4] = { pa[0], pa[1], pa[2], pa[3] };
#define T1(m) b[(m) & 3] = fmaf(dppf<m>(h1), wh1p[m], b[(m) & 3]);
            FOR16(T1)
#undef T1
            float g1 = (b[0] + b[1]) + (b[2] + b[3]);
            cell(g1, r2f, b0, b1, c1, h1);
            pa[0] = gb1 + v1n; pa[1] = 0.f; pa[2] = 0.f; pa[3] = 0.f;
#define TW(m) pa[(m) & 3] = fmaf(dppf<m>(h0n), wi1h[(m) - 8], pa[(m) & 3]);
            FOR8HI(TW)
#undef TW
        }
        setcnt(&flags[2], n + 1, L);
    }

    float h1f[16];
#pragma unroll
    for (int m = 0; m < 16; ++m) h1f[m] = __shfl(h1, m, 16);
    if (L < 10) {
        float o = breg[L];
#pragma unroll
        for (int m = 0; m < 16; ++m) o = fmaf(Wreg[L * 16 + m], h1f[m], o);
        out[L] = o;
    }
}

__global__ __launch_bounds__(128, 1) void lstm_pipe(
    const float* __restrict__ x, const float* __restrict__ gx, int useGx,
    const float* __restrict__ Wih0, const float* __restrict__ Whh0,
    const float* __restrict__ bih0, const float* __restrict__ bhh0,
    const float* __restrict__ Wih1, const float* __restrict__ Whh1,
    const float* __restrict__ bih1, const float* __restrict__ bhh1,
    const float* __restrict__ Wreg, const float* __restrict__ breg,
    float* __restrict__ out)
{
    __shared__ float hv[2][CHK][128];   // 64 KB ring: [0..63]=h0 replicated, [64..127]=v1 partial
    __shared__ int flags[4];

    const int tid = threadIdx.x;
    const int wid = tid >> 6;
    const int L = tid & 63;

    if (tid == 0) { flags[0] = 0; flags[1] = 0; flags[2] = 0; flags[3] = 0; }
    __syncthreads();

    if (wid == 0) {
        if (useGx) run_wave0<true>(gx, x, Whh0, Wih1, Wih0, bih0, bhh0, hv, flags, L);
        else       run_wave0<false>(gx, x, Whh0, Wih1, Wih0, bih0, bhh0, hv, flags, L);
    } else {
        run_wave1(Wih1, Whh1, bih1, bhh1, Wreg, breg, hv, flags, L, out);
    }
}

extern "C" void kernel_launch(void* const* d_in, const int* in_sizes, int n_in,
                              void* d_out, int out_size, void* d_ws, size_t ws_size,
                              hipStream_t stream) {
    const float* x    = (const float*)d_in[0];
    const float* Wih0 = (const float*)d_in[1];
    const float* Whh0 = (const float*)d_in[2];
    const float* bih0 = (const float*)d_in[3];
    const float* bhh0 = (const float*)d_in[4];
    const float* Wih1 = (const float*)d_in[5];
    const float* Whh1 = (const float*)d_in[6];
    const float* bih1 = (const float*)d_in[7];
    const float* bhh1 = (const float*)d_in[8];
    const float* Wreg = (const float*)d_in[9];
    const float* breg = (const float*)d_in[10];

    const size_t need = (size_t)T_LEN * 64 * sizeof(float);
    int useGx = (d_ws != nullptr && ws_size >= need) ? 1 : 0;
    float* gx = (float*)d_ws;

    if (useGx)
        xprep<<<T_LEN / 4, 256, 0, stream>>>(x, Wih0, bih0, bhh0, gx);

    lstm_pipe<<<1, 128, 0, stream>>>(x, gx, useGx,
                                     Wih0, Whh0, bih0, bhh0,
                                     Wih1, Whh1, bih1, bhh1,
                                     Wreg, breg, (float*)d_out);
}